// Round 14
// baseline (282.790 us; speedup 1.0000x reference)
//
#include <hip/hip_runtime.h>
#include <hip/hip_bf16.h>

#define B_ 32
#define T_ 4096
#define H_ 512
#define M_TILE 64    // 2 t x 32 b per tile
#define TPB 8        // tiles per block; NBLK*TPB*M_TILE = 131072 rows
#define NBLK 256     // 1 persistent block per CU
#define NTHREADS 512

typedef __attribute__((ext_vector_type(8))) short short8;
typedef __attribute__((ext_vector_type(8))) __bf16 bf16x8;
typedef __attribute__((ext_vector_type(4))) float f32x4;

__device__ __forceinline__ short f2bf(float f) {
    unsigned u = __builtin_bit_cast(unsigned, f);
    u = (u + 0x7fffu + ((u >> 16) & 1u)) >> 16;
    return (short)u;
}

// packed f32->bf16 (RNE): 8 f32 -> 8 bf16 (16B), 4 instructions
__device__ __forceinline__ short8 pack8(f32x4 a, f32x4 b) {
    union { unsigned u[4]; short8 s; } r;
    asm("v_cvt_pk_bf16_f32 %0, %1, %2" : "=v"(r.u[0]) : "v"(a[0]), "v"(a[1]));
    asm("v_cvt_pk_bf16_f32 %0, %1, %2" : "=v"(r.u[1]) : "v"(a[2]), "v"(a[3]));
    asm("v_cvt_pk_bf16_f32 %0, %1, %2" : "=v"(r.u[2]) : "v"(b[0]), "v"(b[1]));
    asm("v_cvt_pk_bf16_f32 %0, %1, %2" : "=v"(r.u[3]) : "v"(b[2]), "v"(b[3]));
    return r.s;
}

// ---- prep: W2 -> bf16 fragment-packed (verified layout R4-R13, unchanged) ----
// w2f[c][ck][ni][lane][j]: h = c*64+ni*16+(lane&15), k = ck*32+(lane>>4)*8+j
__global__ void prep_w2f(const float* __restrict__ W, short* __restrict__ w2f) {
    int idx = blockIdx.x * 256 + threadIdx.x;   // 0 .. 262143
    int j    = idx & 7;
    int lane = (idx >> 3) & 63;
    int ni   = (idx >> 9) & 3;
    int ck   = (idx >> 11) & 15;
    int c    = (idx >> 15) & 7;
    int h = c * 64 + ni * 16 + (lane & 15);
    int k = ck * 32 + (lane >> 4) * 8 + j;
    w2f[idx] = f2bf(W[h * (2 * H_) + H_ + k]);
}

// ---- prep: hid_proj[b][h] = hidden[b,:]*W1[h,:] + bias[h] (f32 exact) ----
__global__ void prep_hid(const float* __restrict__ hidden,
                         const float* __restrict__ W,
                         const float* __restrict__ bias,
                         float* __restrict__ hidproj) {
    __shared__ float hrow[H_];
    int b = blockIdx.y;
    int h = blockIdx.x * 128 + threadIdx.x;
    for (int i = threadIdx.x; i < H_; i += 128) hrow[i] = hidden[b * H_ + i];
    __syncthreads();
    const float* wr = W + (size_t)h * (2 * H_);
    float acc = bias[h];
#pragma unroll 4
    for (int k = 0; k < H_; k += 4) {
        acc += hrow[k]     * wr[k];
        acc += hrow[k + 1] * wr[k + 1];
        acc += hrow[k + 2] * wr[k + 2];
        acc += hrow[k + 3] * wr[k + 3];
    }
    hidproj[b * H_ + h] = acc;
}

// ---- main: persistent 1-block/CU; gload_lds f32 staging (swizzled source);
//      convert-on-read; half-K ping-pong; SLIM register budget (<128 arch) ----
__global__ __launch_bounds__(NTHREADS, 2)
void attn_main(const float* __restrict__ enc,      // [T*B][H] f32, tile-contiguous
               const float* __restrict__ hidproj,  // [B][H] f32
               const short* __restrict__ w2f,      // frag-packed bf16 W2
               const float* __restrict__ vvec,     // [H]
               float* __restrict__ out)            // [B][T]
{
    __shared__ __align__(16) float lds_f[2][M_TILE * 256];  // 2 x 64 KB f32 half-K
    __shared__ float red[NTHREADS];                          // 2 KB

    const int tid  = threadIdx.x;
    const int lane = tid & 63;
    const int wid  = tid >> 6;          // 0..7: h-block AND staging row group
    const int lo   = lane & 15;
    const int hi4  = lane >> 4;
    const int xm   = lo & 7;            // read-side chunk XOR (row&7)
    const int lane16 = lane << 4;       // byte
    const int gbase = blockIdx.x * TPB;
    const char* encb = (const char*)enc;

    // B stream base
    const short* wbase = w2f + (size_t)wid * 32768 + lane * 8;

    // stage half HF of tile G into BUF: wave stages rows wid*8..wid*8+7.
    // LDS dest linear (HW: lane l at +l*16); global source lane-swizzled so
    // physical chunk p holds logical chunk p^(row&7)  [row&7 == i_].
#define STAGE(G, HF, BUF)                                                         \
    { const char* gb_ = encb + (size_t)(G) * 131072 + (HF) * 1024 + wid * 16384;  \
      _Pragma("unroll")                                                           \
      for (int i_ = 0; i_ < 8; ++i_) {                                            \
        __builtin_amdgcn_global_load_lds(                                         \
            (const __attribute__((address_space(1))) void*)                       \
                (gb_ + i_ * 2048 + (lane16 ^ (i_ << 4))),                         \
            (__attribute__((address_space(3))) void*)                             \
                ((char*)(BUF) + (wid * 8 + i_) * 1024),                           \
            16, 0, 0); } }

    // KSUB: ksub S (0..7) of current half from f32 buffer rb, B-frags BQ.
#define KSUB(S, BQ)                                                               \
    {                                                                             \
        bf16x8 af_[4];                                                            \
        _Pragma("unroll")                                                         \
        for (int mi = 0; mi < 4; ++mi) {                                          \
            int r_ = mi * 16 + lo;                                                \
            const float* rp_ = rb + r_ * 256;                                     \
            f32x4 a0_ = *(const f32x4*)(rp_ + ((((S) * 8 + hi4 * 2)     ^ xm) << 2)); \
            f32x4 a1_ = *(const f32x4*)(rp_ + ((((S) * 8 + hi4 * 2 + 1) ^ xm) << 2)); \
            af_[mi] = __builtin_bit_cast(bf16x8, pack8(a0_, a1_));                \
        }                                                                         \
        __builtin_amdgcn_s_setprio(1);                                            \
        _Pragma("unroll")                                                         \
        for (int mi = 0; mi < 4; ++mi)                                            \
            _Pragma("unroll")                                                     \
            for (int ni = 0; ni < 4; ++ni)                                        \
                acc[mi][ni] = __builtin_amdgcn_mfma_f32_16x16x32_bf16(            \
                    af_[mi], BQ[ni], acc[mi][ni], 0, 0, 0);                       \
        __builtin_amdgcn_s_setprio(0);                                            \
    }

    // KSTEP: 2 ksubs with 2-deep B ring; KK==3 prefetches NXTC (tile-invariant).
#define KSTEP(CK0, KK, NXTC)                                                      \
    {                                                                             \
        _Pragma("unroll")                                                         \
        for (int ni = 0; ni < 4; ++ni)                                            \
            bqB[ni] = *(const bf16x8*)(wbase + (((CK0) + 2 * (KK) + 1) * 4 + ni) * 512); \
        KSUB(2 * (KK), bqA)                                                       \
        _Pragma("unroll")                                                         \
        for (int ni = 0; ni < 4; ++ni)                                            \
            bqA[ni] = *(const bf16x8*)(wbase +                                    \
                ((((KK) == 3 ? (NXTC) : (CK0) + 2 * (KK) + 2)) * 4 + ni) * 512);  \
        KSUB(2 * (KK) + 1, bqB)                                                   \
    }

#define HALF(CK0, NXTC) KSTEP(CK0, 0, NXTC) KSTEP(CK0, 1, NXTC) KSTEP(CK0, 2, NXTC) KSTEP(CK0, 3, NXTC)

    // ---- prologue: stage tile0 half0 -> buf0; first B chunk ----
    STAGE(gbase, 0, &lds_f[0][0])
    asm volatile("s_waitcnt vmcnt(0)" ::: "memory");
    __builtin_amdgcn_s_barrier();

    bf16x8 bqA[4], bqB[4];
#pragma unroll
    for (int ni = 0; ni < 4; ++ni) bqA[ni] = *(const bf16x8*)(wbase + ni * 512);

#pragma unroll 1
    for (int lt = 0; lt < TPB; ++lt) {
        const int g = gbase + lt;

        f32x4 acc[4][4];
#pragma unroll
        for (int i = 0; i < 4; ++i)
#pragma unroll
            for (int j = 0; j < 4; ++j) acc[i][j] = f32x4{0.f, 0.f, 0.f, 0.f};

        // ==== phase 0: stage half1 -> buf1; compute half0 from buf0 ====
        STAGE(g, 1, &lds_f[1][0])
        __builtin_amdgcn_sched_barrier(0);
        {
            const float* rb = &lds_f[0][0];
            HALF(0, 8)
        }
        asm volatile("s_waitcnt vmcnt(0)" ::: "memory");
        __builtin_amdgcn_s_barrier();

        // ==== phase 1: stage next tile half0 -> buf0; compute half1 from buf1 ====
        if (lt + 1 < TPB) {
            STAGE(g + 1, 0, &lds_f[0][0])
            __builtin_amdgcn_sched_barrier(0);
        }
        {
            const float* rb = &lds_f[1][0];
            HALF(8, 0)
        }

        // ---- per-tile epilogue: energy += hid (loaded HERE, not hoisted),
        //      softmax over b, v-dot, cross-wave reduce ----
        {
#pragma unroll
            for (int par = 0; par < 2; ++par)
#pragma unroll
                for (int j = 0; j < 4; ++j) {
                    int b = par * 16 + hi4 * 4 + j;
#pragma unroll
                    for (int ni = 0; ni < 4; ++ni) {
                        float h = hidproj[b * H_ + wid * 64 + ni * 16 + lo];
                        acc[par][ni][j] += h;       // mi = par
                        acc[par + 2][ni][j] += h;   // mi = par+2 (same b, tl2=1)
                    }
                }
        }

        float scp[4][4];
#pragma unroll
        for (int tl2 = 0; tl2 < 2; ++tl2) {
            const int m0 = tl2 * 2, m1 = tl2 * 2 + 1;
#pragma unroll
            for (int ni = 0; ni < 4; ++ni) {
                float mx = -1e30f;
#pragma unroll
                for (int j = 0; j < 4; ++j) {
                    mx = fmaxf(mx, acc[m0][ni][j]);
                    mx = fmaxf(mx, acc[m1][ni][j]);
                }
                mx = fmaxf(mx, __shfl_xor(mx, 16));
                mx = fmaxf(mx, __shfl_xor(mx, 32));
                float e0[4], e1[4];
                float sum = 0.f;
#pragma unroll
                for (int j = 0; j < 4; ++j) {
                    e0[j] = __expf(acc[m0][ni][j] - mx);
                    e1[j] = __expf(acc[m1][ni][j] - mx);
                    sum += e0[j] + e1[j];
                }
                sum += __shfl_xor(sum, 16);
                sum += __shfl_xor(sum, 32);
                float rs = vvec[wid * 64 + ni * 16 + lo] / sum;  // v[h]/denom
#pragma unroll
                for (int j = 0; j < 4; ++j) {
                    if (ni == 0) { scp[m0][j] = e0[j] * rs; scp[m1][j] = e1[j] * rs; }
                    else         { scp[m0][j] += e0[j] * rs; scp[m1][j] += e1[j] * rs; }
                }
            }
        }

#pragma unroll
        for (int mi = 0; mi < 4; ++mi)
#pragma unroll
            for (int j = 0; j < 4; ++j) {
                float x = scp[mi][j];
                x += __shfl_xor(x, 1);
                x += __shfl_xor(x, 2);
                x += __shfl_xor(x, 4);
                x += __shfl_xor(x, 8);
                scp[mi][j] = x;
            }

        if (lo == 0) {
#pragma unroll
            for (int mi = 0; mi < 4; ++mi)
#pragma unroll
                for (int j = 0; j < 4; ++j)
                    red[wid * 64 + mi * 16 + hi4 * 4 + j] = scp[mi][j];
        }

        // single end-of-tile sync: red visible AND next half0 stage drained
        asm volatile("s_waitcnt vmcnt(0) lgkmcnt(0)" ::: "memory");
        __builtin_amdgcn_s_barrier();

        if (tid < M_TILE) {
            float s = 0.f;
#pragma unroll
            for (int w = 0; w < 8; ++w) s += red[w * 64 + tid];
            int b   = tid & 31;
            int tl2 = tid >> 5;
            out[(size_t)b * T_ + (g * 2 + tl2)] = fmaxf(s, 0.f);
        }
    }
#undef HALF
#undef KSTEP
#undef KSUB
#undef STAGE
}

extern "C" void kernel_launch(void* const* d_in, const int* in_sizes, int n_in,
                              void* d_out, int out_size, void* d_ws, size_t ws_size,
                              hipStream_t stream) {
    const float* hidden = (const float*)d_in[0];
    const float* enc    = (const float*)d_in[1];
    const float* W      = (const float*)d_in[2];
    const float* bias   = (const float*)d_in[3];
    const float* v      = (const float*)d_in[4];
    float* out = (float*)d_out;

    float* hidproj = (float*)d_ws;                    // 64 KB
    short* w2f     = (short*)((char*)d_ws + 65536);   // 512 KB

    prep_w2f<<<1024, 256, 0, stream>>>(W, w2f);
    prep_hid<<<dim3(4, 32), 128, 0, stream>>>(hidden, W, bias, hidproj);
    attn_main<<<NBLK, NTHREADS, 0, stream>>>(enc, hidproj, w2f, v, out);
}

// Round 16
// 162.792 us; speedup vs baseline: 1.7371x; 1.7371x over previous
//
#include <hip/hip_runtime.h>
#include <hip/hip_bf16.h>

#define B_ 32
#define T_ 4096
#define H_ 512
#define M_TILE 64    // 2 t x 32 b per block
#define NTHREADS 512 // 8 waves; 2 blocks/CU (LDS 66 KB)

typedef __attribute__((ext_vector_type(8))) short short8;
typedef __attribute__((ext_vector_type(8))) __bf16 bf16x8;
typedef __attribute__((ext_vector_type(4))) float f32x4;

__device__ __forceinline__ short f2bf(float f) {
    unsigned u = __builtin_bit_cast(unsigned, f);
    u = (u + 0x7fffu + ((u >> 16) & 1u)) >> 16;
    return (short)u;
}

// packed f32->bf16 (RNE): 8 f32 -> 8 bf16 (16B), 4 instructions
__device__ __forceinline__ short8 pack8(f32x4 a, f32x4 b) {
    union { unsigned u[4]; short8 s; } r;
    asm("v_cvt_pk_bf16_f32 %0, %1, %2" : "=v"(r.u[0]) : "v"(a[0]), "v"(a[1]));
    asm("v_cvt_pk_bf16_f32 %0, %1, %2" : "=v"(r.u[1]) : "v"(a[2]), "v"(a[3]));
    asm("v_cvt_pk_bf16_f32 %0, %1, %2" : "=v"(r.u[2]) : "v"(b[0]), "v"(b[1]));
    asm("v_cvt_pk_bf16_f32 %0, %1, %2" : "=v"(r.u[3]) : "v"(b[2]), "v"(b[3]));
    return r.s;
}

// ---- prep: W2 -> bf16 fragment-packed (verified layout R4-R14, unchanged) ----
// w2f[c][ck][ni][lane][j]: h = c*64+ni*16+(lane&15), k = ck*32+(lane>>4)*8+j
__global__ void prep_w2f(const float* __restrict__ W, short* __restrict__ w2f) {
    int idx = blockIdx.x * 256 + threadIdx.x;   // 0 .. 262143
    int j    = idx & 7;
    int lane = (idx >> 3) & 63;
    int ni   = (idx >> 9) & 3;
    int ck   = (idx >> 11) & 15;
    int c    = (idx >> 15) & 7;
    int h = c * 64 + ni * 16 + (lane & 15);
    int k = ck * 32 + (lane >> 4) * 8 + j;
    w2f[idx] = f2bf(W[h * (2 * H_) + H_ + k]);
}

// ---- prep: hid_proj[b][h] = hidden[b,:]*W1[h,:] + bias[h] (f32 exact) ----
__global__ void prep_hid(const float* __restrict__ hidden,
                         const float* __restrict__ W,
                         const float* __restrict__ bias,
                         float* __restrict__ hidproj) {
    __shared__ float hrow[H_];
    int b = blockIdx.y;
    int h = blockIdx.x * 128 + threadIdx.x;
    for (int i = threadIdx.x; i < H_; i += 128) hrow[i] = hidden[b * H_ + i];
    __syncthreads();
    const float* wr = W + (size_t)h * (2 * H_);
    float acc = bias[h];
#pragma unroll 4
    for (int k = 0; k < H_; k += 4) {
        acc += hrow[k]     * wr[k];
        acc += hrow[k + 1] * wr[k + 1];
        acc += hrow[k + 2] * wr[k + 2];
        acc += hrow[k + 3] * wr[k + 3];
    }
    hidproj[b * H_ + h] = acc;
}

// ---- main: per-tile block; quarter-K f32 ping-pong via global_load_lds
//      (pre-swizzled source, zero staging registers); convert-on-read ----
__global__ __launch_bounds__(NTHREADS, 4)
void attn_main(const float* __restrict__ enc,      // [T*B][H] f32, tile-contiguous
               const float* __restrict__ hidproj,  // [B][H] f32
               const short* __restrict__ w2f,      // frag-packed bf16 W2
               const float* __restrict__ vvec,     // [H]
               float* __restrict__ out)            // [B][T]
{
    __shared__ __align__(16) float lds_q[2][M_TILE * 128];  // 2 x 32 KB f32 quarter-K
    __shared__ float red[NTHREADS];                          // 2 KB

    const int tid  = threadIdx.x;
    const int lane = tid & 63;
    const int wid  = tid >> 6;          // 0..7: h-block AND staging row group
    const int lo   = lane & 15;
    const int hi4  = lane >> 4;
    const int xm   = lo & 7;            // read-side 16B-chunk XOR (row&7)
    const int t0   = blockIdx.x * 2;
    const char* encb = (const char*)enc + (size_t)blockIdx.x * 131072;  // tile base

    const short* wbase = w2f + (size_t)wid * 32768 + lane * 8;

    // ---- STAGE quarter Q (cols [Q*128,Q*128+128) f32) into BUF ----
    // wave stages rows wid*8..wid*8+7; instr i_ covers rows 2i_,2i_+1 of that group.
    // LDS dest linear (HW adds lane*16); global source col pre-swizzled:
    // physical chunk (l&31) receives logical chunk (l&31)^(row&7).
#define STAGE(Q, BUF)                                                             \
    { const char* gq_ = encb + (size_t)wid * 16384 + (Q) * 512;                   \
      _Pragma("unroll")                                                           \
      for (int i_ = 0; i_ < 4; ++i_) {                                            \
        int rsub_ = 2 * i_ + (lane >> 5);            /* row within group, 0..7 */ \
        __builtin_amdgcn_global_load_lds(                                         \
            (const __attribute__((address_space(1))) void*)                       \
                (gq_ + rsub_ * 2048 + (((lane & 31) ^ (rsub_ & 7)) << 4)),        \
            (__attribute__((address_space(3))) void*)                             \
                ((char*)(BUF) + (wid * 8 + 2 * i_) * 512),                        \
            16, 0, 0); } }

    // ---- KSUB: ksub S (0..3) of current quarter from f32 buffer rb ----
    // af logical 16B chunks c0 = S*8+hi4*2, c0+1; physical = c ^ (row&7).
#define KSUB(S, BQ)                                                               \
    {                                                                             \
        bf16x8 af_[4];                                                            \
        _Pragma("unroll")                                                         \
        for (int mi = 0; mi < 4; ++mi) {                                          \
            int r_ = mi * 16 + lo;                                                \
            const float* rp_ = rb + r_ * 128;                                     \
            f32x4 a0_ = *(const f32x4*)(rp_ + ((((S) * 8 + hi4 * 2)     ^ xm) << 2)); \
            f32x4 a1_ = *(const f32x4*)(rp_ + ((((S) * 8 + hi4 * 2 + 1) ^ xm) << 2)); \
            af_[mi] = __builtin_bit_cast(bf16x8, pack8(a0_, a1_));                \
        }                                                                         \
        __builtin_amdgcn_s_setprio(1);                                            \
        _Pragma("unroll")                                                         \
        for (int mi = 0; mi < 4; ++mi)                                            \
            _Pragma("unroll")                                                     \
            for (int ni = 0; ni < 4; ++ni)                                        \
                acc[mi][ni] = __builtin_amdgcn_mfma_f32_16x16x32_bf16(            \
                    af_[mi], BQ[ni], acc[mi][ni], 0, 0, 0);                       \
        __builtin_amdgcn_s_setprio(0);                                            \
    }

    // quarter Q uses B chunks ck = Q*4 .. Q*4+3 (frag ni of ck at (ck*4+ni)*512).
    // NXTCK = CHUNK index to preload for the next quarter (R15 bug: passed the
    // quarter index here -> loaded ck=1,2,3 instead of 4,8,12).
#define QUARTER(Q, NXTCK)                                                         \
    {                                                                             \
        _Pragma("unroll")                                                         \
        for (int ni = 0; ni < 4; ++ni)                                            \
            bqB[ni] = *(const bf16x8*)(wbase + (((Q) * 4 + 1) * 4 + ni) * 512);   \
        KSUB(0, bqA)                                                              \
        _Pragma("unroll")                                                         \
        for (int ni = 0; ni < 4; ++ni)                                            \
            bqA[ni] = *(const bf16x8*)(wbase + (((Q) * 4 + 2) * 4 + ni) * 512);   \
        KSUB(1, bqB)                                                              \
        _Pragma("unroll")                                                         \
        for (int ni = 0; ni < 4; ++ni)                                            \
            bqB[ni] = *(const bf16x8*)(wbase + (((Q) * 4 + 3) * 4 + ni) * 512);   \
        KSUB(2, bqA)                                                              \
        _Pragma("unroll")                                                         \
        for (int ni = 0; ni < 4; ++ni)                                            \
            bqA[ni] = *(const bf16x8*)(wbase + ((NXTCK) * 4 + ni) * 512);         \
        KSUB(3, bqB)                                                              \
    }

    f32x4 acc[4][4];
#pragma unroll
    for (int i = 0; i < 4; ++i)
#pragma unroll
        for (int j = 0; j < 4; ++j) acc[i][j] = f32x4{0.f, 0.f, 0.f, 0.f};

    // ---- prologue: stage Q0 -> buf0 (exposed once); preload first B chunk ----
    STAGE(0, &lds_q[0][0])
    bf16x8 bqA[4], bqB[4];
#pragma unroll
    for (int ni = 0; ni < 4; ++ni) bqA[ni] = *(const bf16x8*)(wbase + ni * 512);
    asm volatile("s_waitcnt vmcnt(0)" ::: "memory");
    __builtin_amdgcn_s_barrier();

    // ---- 4 phases: stage Q+1 overlapped with compute Q ----
    {
        STAGE(1, &lds_q[1][0])
        __builtin_amdgcn_sched_barrier(0);
        const float* rb = &lds_q[0][0];
        QUARTER(0, 4)
        asm volatile("s_waitcnt vmcnt(0)" ::: "memory");
        __builtin_amdgcn_s_barrier();
    }
    {
        STAGE(2, &lds_q[0][0])
        __builtin_amdgcn_sched_barrier(0);
        const float* rb = &lds_q[1][0];
        QUARTER(1, 8)
        asm volatile("s_waitcnt vmcnt(0)" ::: "memory");
        __builtin_amdgcn_s_barrier();
    }
    {
        STAGE(3, &lds_q[1][0])
        __builtin_amdgcn_sched_barrier(0);
        const float* rb = &lds_q[0][0];
        QUARTER(2, 12)
        asm volatile("s_waitcnt vmcnt(0)" ::: "memory");
        __builtin_amdgcn_s_barrier();
    }
    {
        const float* rb = &lds_q[1][0];
        QUARTER(3, 0)
    }

    // ---- epilogue: energy += hid (loaded here), softmax over b, v-dot, reduce ----
    {
#pragma unroll
        for (int par = 0; par < 2; ++par)
#pragma unroll
            for (int j = 0; j < 4; ++j) {
                int b = par * 16 + hi4 * 4 + j;
#pragma unroll
                for (int ni = 0; ni < 4; ++ni) {
                    float h = hidproj[b * H_ + wid * 64 + ni * 16 + lo];
                    acc[par][ni][j] += h;       // mi = par     (tl2 = 0)
                    acc[par + 2][ni][j] += h;   // mi = par + 2 (tl2 = 1)
                }
            }
    }

    float scp[4][4];
#pragma unroll
    for (int tl2 = 0; tl2 < 2; ++tl2) {
        const int m0 = tl2 * 2, m1 = tl2 * 2 + 1;
#pragma unroll
        for (int ni = 0; ni < 4; ++ni) {
            float mx = -1e30f;
#pragma unroll
            for (int j = 0; j < 4; ++j) {
                mx = fmaxf(mx, acc[m0][ni][j]);
                mx = fmaxf(mx, acc[m1][ni][j]);
            }
            mx = fmaxf(mx, __shfl_xor(mx, 16));
            mx = fmaxf(mx, __shfl_xor(mx, 32));
            float e0[4], e1[4];
            float sum = 0.f;
#pragma unroll
            for (int j = 0; j < 4; ++j) {
                e0[j] = __expf(acc[m0][ni][j] - mx);
                e1[j] = __expf(acc[m1][ni][j] - mx);
                sum += e0[j] + e1[j];
            }
            sum += __shfl_xor(sum, 16);
            sum += __shfl_xor(sum, 32);
            float rs = vvec[wid * 64 + ni * 16 + lo] / sum;  // v[h]/denom
#pragma unroll
            for (int j = 0; j < 4; ++j) {
                if (ni == 0) { scp[m0][j] = e0[j] * rs; scp[m1][j] = e1[j] * rs; }
                else         { scp[m0][j] += e0[j] * rs; scp[m1][j] += e1[j] * rs; }
            }
        }
    }

#pragma unroll
    for (int mi = 0; mi < 4; ++mi)
#pragma unroll
        for (int j = 0; j < 4; ++j) {
            float x = scp[mi][j];
            x += __shfl_xor(x, 1);
            x += __shfl_xor(x, 2);
            x += __shfl_xor(x, 4);
            x += __shfl_xor(x, 8);
            scp[mi][j] = x;
        }

    if (lo == 0) {
#pragma unroll
        for (int mi = 0; mi < 4; ++mi)
#pragma unroll
            for (int j = 0; j < 4; ++j)
                red[wid * 64 + mi * 16 + hi4 * 4 + j] = scp[mi][j];
    }
    asm volatile("s_waitcnt lgkmcnt(0)" ::: "memory");
    __builtin_amdgcn_s_barrier();

    if (tid < M_TILE) {
        float s = 0.f;
#pragma unroll
        for (int w = 0; w < 8; ++w) s += red[w * 64 + tid];
        int b   = tid & 31;
        int tl2 = tid >> 5;
        out[(size_t)b * T_ + (t0 + tl2)] = fmaxf(s, 0.f);
    }
#undef QUARTER
#undef KSUB
#undef STAGE
}

extern "C" void kernel_launch(void* const* d_in, const int* in_sizes, int n_in,
                              void* d_out, int out_size, void* d_ws, size_t ws_size,
                              hipStream_t stream) {
    const float* hidden = (const float*)d_in[0];
    const float* enc    = (const float*)d_in[1];
    const float* W      = (const float*)d_in[2];
    const float* bias   = (const float*)d_in[3];
    const float* v      = (const float*)d_in[4];
    float* out = (float*)d_out;

    float* hidproj = (float*)d_ws;                    // 64 KB
    short* w2f     = (short*)((char*)d_ws + 65536);   // 512 KB

    prep_w2f<<<1024, 256, 0, stream>>>(W, w2f);
    prep_hid<<<dim3(4, 32), 128, 0, stream>>>(hidden, W, bias, hidproj);
    attn_main<<<T_ * B_ / M_TILE, NTHREADS, 0, stream>>>(enc, hidproj, w2f, v, out);
}

// Round 17
// 148.750 us; speedup vs baseline: 1.9011x; 1.0944x over previous
//
#include <hip/hip_runtime.h>
#include <hip/hip_bf16.h>

#define B_ 32
#define T_ 4096
#define H_ 512
#define M_TILE 64    // 2 t x 32 b per block
#define NTHREADS 512 // 8 waves; 2 blocks/CU (LDS 66 KB)

typedef __attribute__((ext_vector_type(8))) short short8;
typedef __attribute__((ext_vector_type(8))) __bf16 bf16x8;
typedef __attribute__((ext_vector_type(4))) float f32x4;

__device__ __forceinline__ short f2bf(float f) {
    unsigned u = __builtin_bit_cast(unsigned, f);
    u = (u + 0x7fffu + ((u >> 16) & 1u)) >> 16;
    return (short)u;
}

// packed f32->bf16 (RNE): 8 f32 -> 8 bf16 (16B), 4 instructions
__device__ __forceinline__ short8 pack8(f32x4 a, f32x4 b) {
    union { unsigned u[4]; short8 s; } r;
    asm("v_cvt_pk_bf16_f32 %0, %1, %2" : "=v"(r.u[0]) : "v"(a[0]), "v"(a[1]));
    asm("v_cvt_pk_bf16_f32 %0, %1, %2" : "=v"(r.u[1]) : "v"(a[2]), "v"(a[3]));
    asm("v_cvt_pk_bf16_f32 %0, %1, %2" : "=v"(r.u[2]) : "v"(b[0]), "v"(b[1]));
    asm("v_cvt_pk_bf16_f32 %0, %1, %2" : "=v"(r.u[3]) : "v"(b[2]), "v"(b[3]));
    return r.s;
}

// ---- prep: W2 -> bf16 fragment-packed (verified layout R4-R16, unchanged) ----
// w2f[c][ck][ni][lane][j]: h = c*64+ni*16+(lane&15), k = ck*32+(lane>>4)*8+j
__global__ void prep_w2f(const float* __restrict__ W, short* __restrict__ w2f) {
    int idx = blockIdx.x * 256 + threadIdx.x;   // 0 .. 262143
    int j    = idx & 7;
    int lane = (idx >> 3) & 63;
    int ni   = (idx >> 9) & 3;
    int ck   = (idx >> 11) & 15;
    int c    = (idx >> 15) & 7;
    int h = c * 64 + ni * 16 + (lane & 15);
    int k = ck * 32 + (lane >> 4) * 8 + j;
    w2f[idx] = f2bf(W[h * (2 * H_) + H_ + k]);
}

// ---- prep: hid_proj[b][h] = hidden[b,:]*W1[h,:] + bias[h] (f32 exact) ----
__global__ void prep_hid(const float* __restrict__ hidden,
                         const float* __restrict__ W,
                         const float* __restrict__ bias,
                         float* __restrict__ hidproj) {
    __shared__ float hrow[H_];
    int b = blockIdx.y;
    int h = blockIdx.x * 128 + threadIdx.x;
    for (int i = threadIdx.x; i < H_; i += 128) hrow[i] = hidden[b * H_ + i];
    __syncthreads();
    const float* wr = W + (size_t)h * (2 * H_);
    float acc = bias[h];
#pragma unroll 4
    for (int k = 0; k < H_; k += 4) {
        acc += hrow[k]     * wr[k];
        acc += hrow[k + 1] * wr[k + 1];
        acc += hrow[k + 2] * wr[k + 2];
        acc += hrow[k + 3] * wr[k + 3];
    }
    hidproj[b * H_ + h] = acc;
}

// ---- finisher: out[b,t] = relu(sp0 + sp1) ----
__global__ void finish(const float* __restrict__ sp, float* __restrict__ out) {
    int i = blockIdx.x * 256 + threadIdx.x;
    out[i] = fmaxf(sp[i] + sp[131072 + i], 0.f);
}

// ---- main: per-tile block, h-split (N=256, eta), acc=32 AGPR;
//      quarter-K f32 ping-pong via global_load_lds (swizzled source);
//      B loaded per-quarter BEFORE staging (vmcnt in-order hazard fix) ----
__global__ __launch_bounds__(NTHREADS, 4)
void attn_main(const float* __restrict__ enc,      // [T*B][H] f32, tile-contiguous
               const float* __restrict__ hidproj,  // [B][H] f32
               const short* __restrict__ w2f,      // frag-packed bf16 W2
               const float* __restrict__ vvec,     // [H]
               float* __restrict__ spart)          // [2][B*T] partial scores
{
    __shared__ __align__(16) float lds_q[2][M_TILE * 128];  // 2 x 32 KB f32 quarter-K
    __shared__ float red[NTHREADS];                          // 2 KB

    const int tid  = threadIdx.x;
    const int lane = tid & 63;
    const int wid  = tid >> 6;          // 0..7
    const int lo   = lane & 15;
    const int hi4  = lane >> 4;
    const int xm   = lo & 7;            // read-side 16B-chunk XOR (row&7)
    const int bid  = blockIdx.x;
    // eta-pair of same tau adjacent mod 8 -> same XCD (L2 shares the A tile)
    const int tau  = ((bid >> 4) << 3) | (bid & 7);   // 0..2047
    const int eta  = (bid >> 3) & 1;                  // 0..1
    const int t0   = tau * 2;
    const char* encb = (const char*)enc + (size_t)tau * 131072;  // tile base

    // wave's h-slice: c-block cblk (64 h), ni offset nib (2 frags of 16 h)
    const int cblk = eta * 4 + (wid >> 1);
    const int nib  = (wid & 1) * 2;
    const short* wbase = w2f + (size_t)cblk * 32768 + lane * 8;

    // ---- STAGE quarter Q (cols [Q*128,Q*128+128) f32) into BUF (R16-verified) ----
#define STAGE(Q, BUF)                                                             \
    { const char* gq_ = encb + (size_t)wid * 16384 + (Q) * 512;                   \
      _Pragma("unroll")                                                           \
      for (int i_ = 0; i_ < 4; ++i_) {                                            \
        int rsub_ = 2 * i_ + (lane >> 5);                                         \
        __builtin_amdgcn_global_load_lds(                                         \
            (const __attribute__((address_space(1))) void*)                       \
                (gq_ + rsub_ * 2048 + (((lane & 31) ^ (rsub_ & 7)) << 4)),        \
            (__attribute__((address_space(3))) void*)                             \
                ((char*)(BUF) + (wid * 8 + 2 * i_) * 512),                        \
            16, 0, 0); } }

    // ---- load the quarter's full B set: 4 chunks x 2 ni = 8 frags (32 regs) ----
#define BLOAD(Q)                                                                  \
    { _Pragma("unroll")                                                           \
      for (int ck_ = 0; ck_ < 4; ++ck_)                                           \
        _Pragma("unroll")                                                         \
        for (int ni_ = 0; ni_ < 2; ++ni_)                                         \
            bq[ck_ * 2 + ni_] = *(const bf16x8*)(wbase +                          \
                ((((Q) * 4 + ck_) * 4) + nib + ni_) * 512); }

    // ---- KSUB: ksub S (0..3) of current quarter from f32 buffer rb ----
#define KSUB(S)                                                                   \
    {                                                                             \
        bf16x8 af_[4];                                                            \
        _Pragma("unroll")                                                         \
        for (int mi = 0; mi < 4; ++mi) {                                          \
            int r_ = mi * 16 + lo;                                                \
            const float* rp_ = rb + r_ * 128;                                     \
            f32x4 a0_ = *(const f32x4*)(rp_ + ((((S) * 8 + hi4 * 2)     ^ xm) << 2)); \
            f32x4 a1_ = *(const f32x4*)(rp_ + ((((S) * 8 + hi4 * 2 + 1) ^ xm) << 2)); \
            af_[mi] = __builtin_bit_cast(bf16x8, pack8(a0_, a1_));                \
        }                                                                         \
        __builtin_amdgcn_s_setprio(1);                                            \
        _Pragma("unroll")                                                         \
        for (int mi = 0; mi < 4; ++mi)                                            \
            _Pragma("unroll")                                                     \
            for (int ni = 0; ni < 2; ++ni)                                        \
                acc[mi][ni] = __builtin_amdgcn_mfma_f32_16x16x32_bf16(            \
                    af_[mi], bq[(S) * 2 + ni], acc[mi][ni], 0, 0, 0);             \
        __builtin_amdgcn_s_setprio(0);                                            \
    }

    f32x4 acc[4][2];
#pragma unroll
    for (int i = 0; i < 4; ++i)
#pragma unroll
        for (int j = 0; j < 2; ++j) acc[i][j] = f32x4{0.f, 0.f, 0.f, 0.f};

    // ---- prologue: stage Q0 -> buf0 (exposed once) ----
    STAGE(0, &lds_q[0][0])
    asm volatile("s_waitcnt vmcnt(0)" ::: "memory");
    __builtin_amdgcn_s_barrier();

    bf16x8 bq[8];

    // ==== phase 0: B(Q0) first, then stage Q1 -> buf1, compute Q0 from buf0 ====
    {
        BLOAD(0)
        __builtin_amdgcn_sched_barrier(0);
        STAGE(1, &lds_q[1][0])
        __builtin_amdgcn_sched_barrier(0);
        const float* rb = &lds_q[0][0];
        KSUB(0) KSUB(1) KSUB(2) KSUB(3)
        asm volatile("s_waitcnt vmcnt(0)" ::: "memory");
        __builtin_amdgcn_s_barrier();
    }
    // ==== phase 1: B(Q1), stage Q2 -> buf0, compute Q1 from buf1 ====
    {
        BLOAD(1)
        __builtin_amdgcn_sched_barrier(0);
        STAGE(2, &lds_q[0][0])
        __builtin_amdgcn_sched_barrier(0);
        const float* rb = &lds_q[1][0];
        KSUB(0) KSUB(1) KSUB(2) KSUB(3)
        asm volatile("s_waitcnt vmcnt(0)" ::: "memory");
        __builtin_amdgcn_s_barrier();
    }
    // ==== phase 2: B(Q2), stage Q3 -> buf1, compute Q2 from buf0 ====
    {
        BLOAD(2)
        __builtin_amdgcn_sched_barrier(0);
        STAGE(3, &lds_q[1][0])
        __builtin_amdgcn_sched_barrier(0);
        const float* rb = &lds_q[0][0];
        KSUB(0) KSUB(1) KSUB(2) KSUB(3)
        asm volatile("s_waitcnt vmcnt(0)" ::: "memory");
        __builtin_amdgcn_s_barrier();
    }
    // ==== phase 3: B(Q3), compute Q3 from buf1 (no stage) ====
    {
        BLOAD(3)
        const float* rb = &lds_q[1][0];
        KSUB(0) KSUB(1) KSUB(2) KSUB(3)
    }

    // ---- epilogue: energy += hid, softmax over b, v-dot, reduce, spart ----
    {
#pragma unroll
        for (int par = 0; par < 2; ++par)
#pragma unroll
            for (int j = 0; j < 4; ++j) {
                int b = par * 16 + hi4 * 4 + j;
#pragma unroll
                for (int ni = 0; ni < 2; ++ni) {
                    float h = hidproj[b * H_ + cblk * 64 + (nib + ni) * 16 + lo];
                    acc[par][ni][j] += h;       // mi = par     (tl2 = 0)
                    acc[par + 2][ni][j] += h;   // mi = par + 2 (tl2 = 1)
                }
            }
    }

    float scp[4][4];
#pragma unroll
    for (int tl2 = 0; tl2 < 2; ++tl2) {
        const int m0 = tl2 * 2, m1 = tl2 * 2 + 1;
#pragma unroll
        for (int ni = 0; ni < 2; ++ni) {
            float mx = -1e30f;
#pragma unroll
            for (int j = 0; j < 4; ++j) {
                mx = fmaxf(mx, acc[m0][ni][j]);
                mx = fmaxf(mx, acc[m1][ni][j]);
            }
            mx = fmaxf(mx, __shfl_xor(mx, 16));
            mx = fmaxf(mx, __shfl_xor(mx, 32));
            float e0[4], e1[4];
            float sum = 0.f;
#pragma unroll
            for (int j = 0; j < 4; ++j) {
                e0[j] = __expf(acc[m0][ni][j] - mx);
                e1[j] = __expf(acc[m1][ni][j] - mx);
                sum += e0[j] + e1[j];
            }
            sum += __shfl_xor(sum, 16);
            sum += __shfl_xor(sum, 32);
            float rs = vvec[cblk * 64 + (nib + ni) * 16 + lo] / sum;
#pragma unroll
            for (int j = 0; j < 4; ++j) {
                if (ni == 0) { scp[m0][j] = e0[j] * rs; scp[m1][j] = e1[j] * rs; }
                else         { scp[m0][j] += e0[j] * rs; scp[m1][j] += e1[j] * rs; }
            }
        }
    }

#pragma unroll
    for (int mi = 0; mi < 4; ++mi)
#pragma unroll
        for (int j = 0; j < 4; ++j) {
            float x = scp[mi][j];
            x += __shfl_xor(x, 1);
            x += __shfl_xor(x, 2);
            x += __shfl_xor(x, 4);
            x += __shfl_xor(x, 8);
            scp[mi][j] = x;
        }

    if (lo == 0) {
#pragma unroll
        for (int mi = 0; mi < 4; ++mi)
#pragma unroll
            for (int j = 0; j < 4; ++j)
                red[wid * 64 + mi * 16 + hi4 * 4 + j] = scp[mi][j];
    }
    asm volatile("s_waitcnt lgkmcnt(0)" ::: "memory");
    __builtin_amdgcn_s_barrier();

    if (tid < M_TILE) {
        float s = 0.f;
#pragma unroll
        for (int w = 0; w < 8; ++w) s += red[w * 64 + tid];
        int b   = tid & 31;
        int tl2 = tid >> 5;
        spart[(size_t)eta * 131072 + (size_t)b * T_ + (t0 + tl2)] = s;
    }
#undef KSUB
#undef BLOAD
#undef STAGE
}

extern "C" void kernel_launch(void* const* d_in, const int* in_sizes, int n_in,
                              void* d_out, int out_size, void* d_ws, size_t ws_size,
                              hipStream_t stream) {
    const float* hidden = (const float*)d_in[0];
    const float* enc    = (const float*)d_in[1];
    const float* W      = (const float*)d_in[2];
    const float* bias   = (const float*)d_in[3];
    const float* v      = (const float*)d_in[4];
    float* out = (float*)d_out;

    float* hidproj = (float*)d_ws;                           // 64 KB
    short* w2f     = (short*)((char*)d_ws + 65536);          // 512 KB
    float* spart   = (float*)((char*)d_ws + 65536 + 524288); // 1 MB

    prep_w2f<<<1024, 256, 0, stream>>>(W, w2f);
    prep_hid<<<dim3(4, 32), 128, 0, stream>>>(hidden, W, bias, hidproj);
    attn_main<<<4096, NTHREADS, 0, stream>>>(enc, hidproj, w2f, v, spart);
    finish<<<512, 256, 0, stream>>>(spart, out);
}

// Round 18
// 144.783 us; speedup vs baseline: 1.9532x; 1.0274x over previous
//
#include <hip/hip_runtime.h>
#include <hip/hip_bf16.h>

#define B_ 32
#define T_ 4096
#define H_ 512
#define M_TILE 32    // 1 t x 32 b per block
#define NTHREADS 512 // 8 waves; 4 blocks/CU (LDS 33 KB)

typedef __attribute__((ext_vector_type(4))) short short4v;
typedef __attribute__((ext_vector_type(8))) __bf16 bf16x8;
typedef __attribute__((ext_vector_type(4))) float f32x4;

__device__ __forceinline__ short f2bf(float f) {
    unsigned u = __builtin_bit_cast(unsigned, f);
    u = (u + 0x7fffu + ((u >> 16) & 1u)) >> 16;
    return (short)u;
}

// packed f32->bf16 (RNE): f32x4 -> 4 bf16 (8B), 2 instructions
__device__ __forceinline__ short4v pack4(f32x4 a) {
    union { unsigned u[2]; short4v s; } r;
    asm("v_cvt_pk_bf16_f32 %0, %1, %2" : "=v"(r.u[0]) : "v"(a[0]), "v"(a[1]));
    asm("v_cvt_pk_bf16_f32 %0, %1, %2" : "=v"(r.u[1]) : "v"(a[2]), "v"(a[3]));
    return r.s;
}

// ---- prep: W2 -> bf16 fragment-packed (verified layout R4-R17, unchanged) ----
// w2f[c][ck][ni][lane][j]: h = c*64+ni*16+(lane&15), k = ck*32+(lane>>4)*8+j
__global__ void prep_w2f(const float* __restrict__ W, short* __restrict__ w2f) {
    int idx = blockIdx.x * 256 + threadIdx.x;   // 0 .. 262143
    int j    = idx & 7;
    int lane = (idx >> 3) & 63;
    int ni   = (idx >> 9) & 3;
    int ck   = (idx >> 11) & 15;
    int c    = (idx >> 15) & 7;
    int h = c * 64 + ni * 16 + (lane & 15);
    int k = ck * 32 + (lane >> 4) * 8 + j;
    w2f[idx] = f2bf(W[h * (2 * H_) + H_ + k]);
}

// ---- prep: hid_proj[b][h] = hidden[b,:]*W1[h,:] + bias[h] (f32 exact) ----
__global__ void prep_hid(const float* __restrict__ hidden,
                         const float* __restrict__ W,
                         const float* __restrict__ bias,
                         float* __restrict__ hidproj) {
    __shared__ float hrow[H_];
    int b = blockIdx.y;
    int h = blockIdx.x * 128 + threadIdx.x;
    for (int i = threadIdx.x; i < H_; i += 128) hrow[i] = hidden[b * H_ + i];
    __syncthreads();
    const float* wr = W + (size_t)h * (2 * H_);
    float acc = bias[h];
#pragma unroll 4
    for (int k = 0; k < H_; k += 4) {
        acc += hrow[k]     * wr[k];
        acc += hrow[k + 1] * wr[k + 1];
        acc += hrow[k + 2] * wr[k + 2];
        acc += hrow[k + 3] * wr[k + 3];
    }
    hidproj[b * H_ + h] = acc;
}

// ---- finisher: out[b,t] = relu(sp0 + sp1) ----
__global__ void finish(const float* __restrict__ sp, float* __restrict__ out) {
    int i = blockIdx.x * 256 + threadIdx.x;
    out[i] = fmaxf(sp[i] + sp[131072 + i], 0.f);
}

// ---- main: max-TLP. 32-row tile, h-split (N=256), acc=16 AGPR, 4 blocks/CU.
//      Stage once (coalesced f32 -> cvt_pk -> swizzled 8B ds_write), 1 sync,
//      zero-barrier compute (64 MFMA/wave), epilogue. ----
__global__ __launch_bounds__(NTHREADS, 4)
void attn_main(const float* __restrict__ enc,      // [T*B][H] f32, tile-contiguous
               const float* __restrict__ hidproj,  // [B][H] f32
               const short* __restrict__ w2f,      // frag-packed bf16 W2
               const float* __restrict__ vvec,     // [H]
               float* __restrict__ spart)          // [2][B*T] partial scores
{
    __shared__ __align__(16) short lds_a[M_TILE * H_];  // 32 KB bf16 full-K tile
    __shared__ float red[8 * M_TILE];                   // 1 KB

    const int tid  = threadIdx.x;
    const int lane = tid & 63;
    const int wid  = tid >> 6;          // 0..7
    const int lo   = lane & 15;
    const int hi4  = lane >> 4;
    const int xm   = lo & 7;
    const int bid  = blockIdx.x;
    // eta-pair of same tau adjacent mod 8 -> same XCD (L2 shares the A tile)
    const int tau  = ((bid >> 4) << 3) | (bid & 7);   // 0..4095 (t index)
    const int eta  = (bid >> 3) & 1;                  // 0..1

    // wave's h-slice: c-block cblk (64 h), ni offset nib (2 frags of 16 h)
    const int cblk = eta * 4 + (wid >> 1);
    const int nib  = (wid & 1) * 2;
    const short* wbase = w2f + (size_t)cblk * 32768 + lane * 8;

    // ================== stage full 32x512 tile (64 KB f32 -> 32 KB bf16) =====
    // instr i: flat f32 = i*2048 + tid*4 -> row = i*4 + (tid>>7), col = 4*(tid&127)
    // per wave-instr: one contiguous 1KB row segment (fully coalesced).
    // LDS: 8-bf16 chunk cb = (tid&127)>>1, half = (tid&1)*8B, chunk swz ^(row&7).
    {
        const float* ap = enc + (size_t)tau * (M_TILE * H_) + tid * 4;
        const int rbase = tid >> 7;
        const int cb    = (tid & 127) >> 1;
        const int hb    = (tid & 1) * 8;
        char* lb = (char*)lds_a;
#define STW(I, X) { int r_ = (I) * 4 + rbase;                                     \
        *(short4v*)(lb + r_ * 1024 + (((cb) ^ (r_ & 7)) << 4) + hb) = pack4(X); }
        f32x4 x0, x1, x2, x3;
        x0 = *(const f32x4*)(ap + 0 * 2048);
        x1 = *(const f32x4*)(ap + 1 * 2048);
        x2 = *(const f32x4*)(ap + 2 * 2048);
        x3 = *(const f32x4*)(ap + 3 * 2048);
        STW(0, x0) STW(1, x1) STW(2, x2) STW(3, x3)
        x0 = *(const f32x4*)(ap + 4 * 2048);
        x1 = *(const f32x4*)(ap + 5 * 2048);
        x2 = *(const f32x4*)(ap + 6 * 2048);
        x3 = *(const f32x4*)(ap + 7 * 2048);
        STW(4, x0) STW(5, x1) STW(6, x2) STW(7, x3)
#undef STW
    }
    asm volatile("s_waitcnt lgkmcnt(0)" ::: "memory");
    __builtin_amdgcn_s_barrier();   // the ONLY pre-epilogue barrier

    // ================== compute: 16 ksubs, zero barriers =====================
    f32x4 acc[2][2];
#pragma unroll
    for (int i = 0; i < 2; ++i)
#pragma unroll
        for (int j = 0; j < 2; ++j) acc[i][j] = f32x4{0.f, 0.f, 0.f, 0.f};

#define BLD(DST, CK)                                                              \
    { _Pragma("unroll")                                                           \
      for (int ni_ = 0; ni_ < 2; ++ni_)                                           \
          DST[ni_] = *(const bf16x8*)(wbase + (((CK) * 4) + nib + ni_) * 512); }

#define KSUB(S, BQ)                                                               \
    {                                                                             \
        bf16x8 af_[2];                                                            \
        _Pragma("unroll")                                                         \
        for (int mi = 0; mi < 2; ++mi) {                                          \
            int r_ = mi * 16 + lo;                                                \
            af_[mi] = *(const bf16x8*)((char*)lds_a + r_ * 1024 +                 \
                                       (((((S) * 4) + hi4) ^ xm) << 4));          \
        }                                                                         \
        __builtin_amdgcn_s_setprio(1);                                            \
        _Pragma("unroll")                                                         \
        for (int mi = 0; mi < 2; ++mi)                                            \
            _Pragma("unroll")                                                     \
            for (int ni = 0; ni < 2; ++ni)                                        \
                acc[mi][ni] = __builtin_amdgcn_mfma_f32_16x16x32_bf16(            \
                    af_[mi], BQ[ni], acc[mi][ni], 0, 0, 0);                       \
        __builtin_amdgcn_s_setprio(0);                                            \
    }

#define KPAIR(S)                                                                  \
    BLD(bqB, (S) + 1)                                                             \
    KSUB((S), bqA)                                                                \
    BLD(bqA, ((S) + 2) & 15)                                                      \
    KSUB((S) + 1, bqB)

    bf16x8 bqA[2], bqB[2];
    BLD(bqA, 0)
    KPAIR(0) KPAIR(2) KPAIR(4) KPAIR(6)
    KPAIR(8) KPAIR(10) KPAIR(12) KPAIR(14)
#undef KPAIR
#undef KSUB
#undef BLD

    // ================== epilogue ==============================================
    // bias-add: b = mi*16 + hi4*4 + j; h = cblk*64 + (nib+ni)*16 + lo
    {
#pragma unroll
        for (int mi = 0; mi < 2; ++mi)
#pragma unroll
            for (int j = 0; j < 4; ++j) {
                int b = mi * 16 + hi4 * 4 + j;
#pragma unroll
                for (int ni = 0; ni < 2; ++ni)
                    acc[mi][ni][j] += hidproj[b * H_ + cblk * 64 + (nib + ni) * 16 + lo];
            }
    }

    // softmax over b (32 rows: mi,j in-reg + shfl 16/32), fold v[h]/sum
    float scp[2][4];
#pragma unroll
    for (int ni = 0; ni < 2; ++ni) {
        float mx = -1e30f;
#pragma unroll
        for (int mi = 0; mi < 2; ++mi)
#pragma unroll
            for (int j = 0; j < 4; ++j) mx = fmaxf(mx, acc[mi][ni][j]);
        mx = fmaxf(mx, __shfl_xor(mx, 16));
        mx = fmaxf(mx, __shfl_xor(mx, 32));
        float e[2][4];
        float sum = 0.f;
#pragma unroll
        for (int mi = 0; mi < 2; ++mi)
#pragma unroll
            for (int j = 0; j < 4; ++j) {
                e[mi][j] = __expf(acc[mi][ni][j] - mx);
                sum += e[mi][j];
            }
        sum += __shfl_xor(sum, 16);
        sum += __shfl_xor(sum, 32);
        float rs = vvec[cblk * 64 + (nib + ni) * 16 + lo] / sum;
#pragma unroll
        for (int mi = 0; mi < 2; ++mi)
#pragma unroll
            for (int j = 0; j < 4; ++j) {
                if (ni == 0) scp[mi][j]  = e[mi][j] * rs;
                else         scp[mi][j] += e[mi][j] * rs;
            }
    }

    // reduce over the 16 lo-lanes (different h, same b)
#pragma unroll
    for (int mi = 0; mi < 2; ++mi)
#pragma unroll
        for (int j = 0; j < 4; ++j) {
            float x = scp[mi][j];
            x += __shfl_xor(x, 1);
            x += __shfl_xor(x, 2);
            x += __shfl_xor(x, 4);
            x += __shfl_xor(x, 8);
            scp[mi][j] = x;
        }

    if (lo == 0) {
#pragma unroll
        for (int mi = 0; mi < 2; ++mi)
#pragma unroll
            for (int j = 0; j < 4; ++j)
                red[wid * M_TILE + mi * 16 + hi4 * 4 + j] = scp[mi][j];
    }
    asm volatile("s_waitcnt lgkmcnt(0)" ::: "memory");
    __builtin_amdgcn_s_barrier();

    if (tid < M_TILE) {
        float s = 0.f;
#pragma unroll
        for (int w = 0; w < 8; ++w) s += red[w * M_TILE + tid];
        spart[(size_t)eta * 131072 + (size_t)tid * T_ + tau] = s;
    }
}

extern "C" void kernel_launch(void* const* d_in, const int* in_sizes, int n_in,
                              void* d_out, int out_size, void* d_ws, size_t ws_size,
                              hipStream_t stream) {
    const float* hidden = (const float*)d_in[0];
    const float* enc    = (const float*)d_in[1];
    const float* W      = (const float*)d_in[2];
    const float* bias   = (const float*)d_in[3];
    const float* v      = (const float*)d_in[4];
    float* out = (float*)d_out;

    float* hidproj = (float*)d_ws;                           // 64 KB
    short* w2f     = (short*)((char*)d_ws + 65536);          // 512 KB
    float* spart   = (float*)((char*)d_ws + 65536 + 524288); // 1 MB

    prep_w2f<<<1024, 256, 0, stream>>>(W, w2f);
    prep_hid<<<dim3(4, 32), 128, 0, stream>>>(hidden, W, bias, hidproj);
    attn_main<<<8192, NTHREADS, 0, stream>>>(enc, hidproj, w2f, v, spart);
    finish<<<512, 256, 0, stream>>>(spart, out);
}